// Round 1
// 313.018 us; speedup vs baseline: 1.2409x; 1.2409x over previous
//
#include <hip/hip_runtime.h>
#include <math.h>

// Problem constants
#define NF 5
#define NB 8
#define NC 64
#define HW 16384
#define NK 320               // NF*NC
#define FSTRIDE (NB*NC*HW)   // elements per frame = 8388608

// ws layout (floats)
#define EN_FLOATS    (NB*NC*8)   // 4096: per (b,c): E0..E3, N0..N3
#define ALPHA_FLOATS (NB*NK)     // 2560

#define OST2 132             // padded LDS row stride for o tile (132%32==4 -> conflict-free-ish)

// ---------------- k0: pack origin_w [64][320] -> Wp[cg=4][k=320][16] ----------------
// Wave w of k1 owns channels 16w..16w+15; its W slice becomes 320 contiguous
// 16-float rows -> wave-uniform addresses -> scalar (SMEM) loads.
__global__ void k0_wp(const float* __restrict__ W, float* __restrict__ Wp){
    int idx = blockIdx.x*256 + threadIdx.x;
    if (idx < NC*NK){
        int c = idx / NK;
        int k = idx - c*NK;
        Wp[((c>>4)*NK + k)*16 + (c&15)] = W[idx];
    }
}

// ---------------- k1: fused GEMM + E/N, scalar-W design ----------------
// Block = 256 thr = 4 waves, grid = 1024 (b = blk>>7, s0 = (blk&127)*128).
// Wave w owns channels c0=16w..+15 (wave-uniform -> W/bias via s_load, FMAs
// read SGPR operands directly); lane l owns spatial pair s0+2l.
// Hot loop has NO LDS, NO barriers: per k = 1 coalesced float2 X load (512B/row
// chunks, each row chunk hit once per wave, 4 waves share via L1) + 32 FMAs.
// 32 acc VGPRs/thread -- below the 64-acc spill cliff from earlier rounds.
// LDS (33.8 KB) only for the one-shot o dump -> 4 blocks/CU, 16 waves/CU.
__global__ __launch_bounds__(256, 4) void k1_fused(
    const float* __restrict__ inp, const float* __restrict__ Wp,
    const float* __restrict__ bias, float* __restrict__ EN)
{
    __shared__ float Ol[64*OST2];   // 33792 B: o tile [64 c][128 s], stride OST2

    const int tid = threadIdx.x;
    const int l   = tid & 63;                                   // lane
    const int wv  = __builtin_amdgcn_readfirstlane(tid >> 6);   // wave 0..3 (uniform)
    const int c0  = wv << 4;                                    // 16 channels / wave
    const int b   = blockIdx.x >> 7;
    const int s0  = (blockIdx.x & 127) << 7;                    // 128-float window

    // ---- accumulators, bias-initialized (uniform scalar loads) ----
    float2 a0,a1,a2,a3,a4,a5,a6,a7,a8,a9,a10,a11,a12,a13,a14,a15;
    {
        float4 b0 = *reinterpret_cast<const float4*>(bias + c0);
        float4 b1 = *reinterpret_cast<const float4*>(bias + c0 + 4);
        float4 b2 = *reinterpret_cast<const float4*>(bias + c0 + 8);
        float4 b3 = *reinterpret_cast<const float4*>(bias + c0 + 12);
        a0  = make_float2(b0.x,b0.x); a1  = make_float2(b0.y,b0.y);
        a2  = make_float2(b0.z,b0.z); a3  = make_float2(b0.w,b0.w);
        a4  = make_float2(b1.x,b1.x); a5  = make_float2(b1.y,b1.y);
        a6  = make_float2(b1.z,b1.z); a7  = make_float2(b1.w,b1.w);
        a8  = make_float2(b2.x,b2.x); a9  = make_float2(b2.y,b2.y);
        a10 = make_float2(b2.z,b2.z); a11 = make_float2(b2.w,b2.w);
        a12 = make_float2(b3.x,b3.x); a13 = make_float2(b3.y,b3.y);
        a14 = make_float2(b3.z,b3.z); a15 = make_float2(b3.w,b3.w);
    }

    const float* wbase = Wp + (size_t)wv * NK * 16;   // this wave's 20 KB W slice

#define FMA2(A, WS) A.x = fmaf(WS, xv.x, A.x); A.y = fmaf(WS, xv.y, A.y);

#pragma unroll 1
    for (int f=0; f<NF; ++f){
        const float* xp = inp + (size_t)(f*NB + b)*NC*HW + s0 + (l << 1);
        const float* wf = wbase + f*64*16;
#pragma unroll 4
        for (int k=0; k<64; ++k){
            float2 xv = *reinterpret_cast<const float2*>(xp);
            xp += HW;
            const float* wk = wf + (k << 4);          // uniform -> s_load_dwordx4 x4
            float4 w0 = *reinterpret_cast<const float4*>(wk);
            float4 w1 = *reinterpret_cast<const float4*>(wk + 4);
            float4 w2 = *reinterpret_cast<const float4*>(wk + 8);
            float4 w3 = *reinterpret_cast<const float4*>(wk + 12);
            FMA2(a0, w0.x) FMA2(a1, w0.y) FMA2(a2, w0.z) FMA2(a3, w0.w)
            FMA2(a4, w1.x) FMA2(a5, w1.y) FMA2(a6, w1.z) FMA2(a7, w1.w)
            FMA2(a8, w2.x) FMA2(a9, w2.y) FMA2(a10,w2.z) FMA2(a11,w2.w)
            FMA2(a12,w3.x) FMA2(a13,w3.y) FMA2(a14,w3.z) FMA2(a15,w3.w)
        }
    }
#undef FMA2

    // ---- dump o to LDS: Ol[c][s], stride OST2 ----
    {
        float* od = Ol + (size_t)c0*OST2 + (l << 1);
        *reinterpret_cast<float2*>(od +  0*OST2) = a0;
        *reinterpret_cast<float2*>(od +  1*OST2) = a1;
        *reinterpret_cast<float2*>(od +  2*OST2) = a2;
        *reinterpret_cast<float2*>(od +  3*OST2) = a3;
        *reinterpret_cast<float2*>(od +  4*OST2) = a4;
        *reinterpret_cast<float2*>(od +  5*OST2) = a5;
        *reinterpret_cast<float2*>(od +  6*OST2) = a6;
        *reinterpret_cast<float2*>(od +  7*OST2) = a7;
        *reinterpret_cast<float2*>(od +  8*OST2) = a8;
        *reinterpret_cast<float2*>(od +  9*OST2) = a9;
        *reinterpret_cast<float2*>(od + 10*OST2) = a10;
        *reinterpret_cast<float2*>(od + 11*OST2) = a11;
        *reinterpret_cast<float2*>(od + 12*OST2) = a12;
        *reinterpret_cast<float2*>(od + 13*OST2) = a13;
        *reinterpret_cast<float2*>(od + 14*OST2) = a14;
        *reinterpret_cast<float2*>(od + 15*OST2) = a15;
    }
    __syncthreads();

    // ---- Phase B: thread = (c = tid>>2, i = tid&3), sums the 128-s window ----
    // x4/xi rows were read by this block in Phase A -> L1/L2-hot.
    const int c  = tid >> 2;
    const int ii = tid & 3;
    const float* orow = Ol + c*OST2;
    const float* x4r  = inp + (size_t)((4*NB + b)*NC + c)*HW + s0;
    const float* xir  = inp + (size_t)((ii*NB + b)*NC + c)*HW + s0;
    float e = 0.f, n = 0.f;
#pragma unroll 4
    for (int j=0; j<32; ++j){
        float4 ov = *reinterpret_cast<const float4*>(orow + (j<<2));
        float4 x4 = *reinterpret_cast<const float4*>(x4r  + (j<<2));
        float4 xi = *reinterpret_cast<const float4*>(xir  + (j<<2));
        float d0 = x4.x - xi.x, d1 = x4.y - xi.y;
        float d2 = x4.z - xi.z, d3 = x4.w - xi.w;
        n = fmaf(d0,d0, fmaf(d1,d1, fmaf(d2,d2, fmaf(d3,d3, n))));
        e = fmaf(ov.x,d0, fmaf(ov.y,d1, fmaf(ov.z,d2, fmaf(ov.w,d3, e))));
    }
    float* enb = EN + ((size_t)b*NC + c)*8;
    atomicAdd(&enb[ii],     e);
    atomicAdd(&enb[4 + ii], n);
}

// ---------------- k2: finalize coef -> alpha ----------------
__global__ void k2_coef(const float* __restrict__ EN, const float* __restrict__ out_w,
                        float* __restrict__ alpha)
{
    int tid = threadIdx.x;          // 512 = NB*NC
    int b = tid >> 6, c = tid & 63;
    const float* e = EN + (b*NC + c)*8;
    float w1 = out_w[c], w2 = out_w[NC + c];
    float csum = 0.f;
#pragma unroll
    for (int i=0; i<4; ++i){
        float nc = fmaxf(sqrtf(e[4+i]), 1e-12f);
        float coef = e[i] / (nc*nc);
        alpha[b*NK + i*NC + c] = -w1*coef;
        csum += coef;
    }
    alpha[b*NK + 4*NC + c] = w1*csum + w2;
}

// ---------------- k3: y[b,s] = sum_r alpha[b,r]*inp[r,b,s] + out_b ----------------
// v2: the old 256x128 launch was 2 waves/CU (6% occupancy) -> latency-bound at
// ~1 TB/s. Now grid = 2048 = (b:8) x (swin:64 of 256 floats) x (rowgroup:4 of 80
// rows); block 256 thr further splits rows 4-way (20 rows/thread). 8 blocks/CU,
// 32 waves/CU. Loads: float4, 1 KB contiguous per row chunk. Partials reduced
// through LDS, then 4 atomicAdds per surviving lane into zero-init'd y.
__global__ __launch_bounds__(256) void k3_out(const float* __restrict__ inp,
        const float* __restrict__ alpha, const float* __restrict__ out_b,
        float* __restrict__ y)
{
    __shared__ float  Al[80];
    __shared__ float4 P[256];
    const int tid = threadIdx.x;
    const int blk = blockIdx.x;
    const int b   = blk >> 8;            // 8
    const int sw  = (blk >> 2) & 63;     // 64 spatial windows
    const int rg  = blk & 3;             // 4 row groups of 80
    const int s0  = sw << 8;             // 256-float window
    const int sg  = tid & 63;            // float4 slot
    const int rg2 = tid >> 6;            // 4 sub-groups of 20 rows

    if (tid < 20)
        reinterpret_cast<float4*>(Al)[tid] =
            reinterpret_cast<const float4*>(alpha + b*NK + rg*80)[tid];
    __syncthreads();

    float4 acc = make_float4(0.f, 0.f, 0.f, 0.f);
    const int rbase = rg*80 + rg2*20;
#pragma unroll 4
    for (int j=0; j<20; ++j){
        int r = rbase + j;
        const float* p = inp + (size_t)(((r>>6)*NB + b)*NC + (r&63))*HW + s0 + (sg<<2);
        float4 xv = *reinterpret_cast<const float4*>(p);
        float  w  = Al[rg2*20 + j];
        acc.x = fmaf(w, xv.x, acc.x); acc.y = fmaf(w, xv.y, acc.y);
        acc.z = fmaf(w, xv.z, acc.z); acc.w = fmaf(w, xv.w, acc.w);
    }
    P[tid] = acc;
    __syncthreads();
    if (tid < 64){
        float4 r0 = P[tid], r1 = P[tid+64], r2 = P[tid+128], r3 = P[tid+192];
        float vx = r0.x + r1.x + r2.x + r3.x;
        float vy = r0.y + r1.y + r2.y + r3.y;
        float vz = r0.z + r1.z + r2.z + r3.z;
        float vw = r0.w + r1.w + r2.w + r3.w;
        if (rg == 0){                    // bias added exactly once per output
            float bb = out_b[0];
            vx += bb; vy += bb; vz += bb; vw += bb;
        }
        float* yp = y + (size_t)b*HW + s0 + (tid << 2);
        atomicAdd(yp + 0, vx);
        atomicAdd(yp + 1, vy);
        atomicAdd(yp + 2, vz);
        atomicAdd(yp + 3, vw);
    }
}

extern "C" void kernel_launch(void* const* d_in, const int* in_sizes, int n_in,
                              void* d_out, int out_size, void* d_ws, size_t ws_size,
                              hipStream_t stream)
{
    const float* inp      = (const float*)d_in[0];
    const float* origin_w = (const float*)d_in[1];
    const float* origin_b = (const float*)d_in[2];
    const float* out_w    = (const float*)d_in[3];
    const float* out_b    = (const float*)d_in[4];
    float* y  = (float*)d_out;
    float* ws = (float*)d_ws;

    float* EN    = ws;                              // 4096 floats
    float* alpha = ws + EN_FLOATS;                  // 2560 floats
    float* Wp    = ws + EN_FLOATS + ALPHA_FLOATS;   // 20480 floats

    hipMemsetAsync(EN, 0, EN_FLOATS*sizeof(float), stream);
    hipMemsetAsync(y,  0, (size_t)NB*HW*sizeof(float), stream);
    k0_wp   <<<(NC*NK + 255)/256, 256, 0, stream>>>(origin_w, Wp);
    k1_fused<<<1024, 256, 0, stream>>>(inp, Wp, origin_b, EN);
    k2_coef <<<1, NB*NC, 0, stream>>>(EN, out_w, alpha);
    k3_out  <<<2048, 256, 0, stream>>>(inp, alpha, out_b, y);
}